// Round 1
// baseline (3712.476 us; speedup 1.0000x reference)
//
#include <hip/hip_runtime.h>

#define N_NODES_C 100000
#define N_EDGES_C 3200000
#define DDIM 512   // D_IN == D_OUT == 512

// ---------------------------------------------------------------------------
// Kernel 1: CSR row pointers from sorted edge_dst. rp[n] = lower_bound(dst, n).
// Segment for node n is [rp[n], rp[n+1]).
// ---------------------------------------------------------------------------
__global__ __launch_bounds__(256) void build_rowptr(const int* __restrict__ dst,
                                                    int* __restrict__ rp) {
    int n = blockIdx.x * blockDim.x + threadIdx.x;
    if (n > N_NODES_C) return;
    int lo = 0, hi = N_EDGES_C;
    while (lo < hi) {
        int mid = (lo + hi) >> 1;
        if (dst[mid] < n) lo = mid + 1;
        else hi = mid;
    }
    rp[n] = lo;
}

// ---------------------------------------------------------------------------
// Kernel 2: fp32 tiled GEMM  C[M,512] = A[M,512] @ B[512,512]
// 64x64 tile, BK=16, 256 threads, 4x4 accum per thread.
// ---------------------------------------------------------------------------
#define BM 64
#define BN 64
#define BK 16

__global__ __launch_bounds__(256) void gemm_f32(const float* __restrict__ A,
                                                const float* __restrict__ B,
                                                float* __restrict__ C, int M) {
    __shared__ float sA[BK][BM + 4];  // +4 pad: breaks 4-way write conflict
    __shared__ float sB[BK][BN];

    const int tid = threadIdx.x;
    const int tx = tid & 15;      // output col group
    const int ty = tid >> 4;      // output row group
    const int m0 = blockIdx.x * BM;
    const int n0 = blockIdx.y * BN;

    // A-load mapping: float4 per thread, 64 rows x 16 cols
    const int ar = tid >> 2;           // 0..63
    const int ac = (tid & 3) * 4;      // 0,4,8,12
    // B-load mapping: float4 per thread, 16 rows x 64 cols
    const int br = tid >> 4;           // 0..15
    const int bc = (tid & 15) * 4;     // 0..60

    float acc[4][4] = {};

    for (int k0 = 0; k0 < DDIM; k0 += BK) {
        float4 a4 = make_float4(0.f, 0.f, 0.f, 0.f);
        const int gm = m0 + ar;
        if (gm < M)
            a4 = *(const float4*)&A[(size_t)gm * DDIM + k0 + ac];
        sA[ac + 0][ar] = a4.x;
        sA[ac + 1][ar] = a4.y;
        sA[ac + 2][ar] = a4.z;
        sA[ac + 3][ar] = a4.w;

        float4 b4 = *(const float4*)&B[(size_t)(k0 + br) * DDIM + n0 + bc];
        *(float4*)&sB[br][bc] = b4;

        __syncthreads();

#pragma unroll
        for (int k = 0; k < BK; ++k) {
            float4 av = *(float4*)&sA[k][ty * 4];
            float4 bv = *(float4*)&sB[k][tx * 4];
            acc[0][0] = fmaf(av.x, bv.x, acc[0][0]);
            acc[0][1] = fmaf(av.x, bv.y, acc[0][1]);
            acc[0][2] = fmaf(av.x, bv.z, acc[0][2]);
            acc[0][3] = fmaf(av.x, bv.w, acc[0][3]);
            acc[1][0] = fmaf(av.y, bv.x, acc[1][0]);
            acc[1][1] = fmaf(av.y, bv.y, acc[1][1]);
            acc[1][2] = fmaf(av.y, bv.z, acc[1][2]);
            acc[1][3] = fmaf(av.y, bv.w, acc[1][3]);
            acc[2][0] = fmaf(av.z, bv.x, acc[2][0]);
            acc[2][1] = fmaf(av.z, bv.y, acc[2][1]);
            acc[2][2] = fmaf(av.z, bv.z, acc[2][2]);
            acc[2][3] = fmaf(av.z, bv.w, acc[2][3]);
            acc[3][0] = fmaf(av.w, bv.x, acc[3][0]);
            acc[3][1] = fmaf(av.w, bv.y, acc[3][1]);
            acc[3][2] = fmaf(av.w, bv.z, acc[3][2]);
            acc[3][3] = fmaf(av.w, bv.w, acc[3][3]);
        }
        __syncthreads();
    }

#pragma unroll
    for (int i = 0; i < 4; ++i) {
        const int m = m0 + ty * 4 + i;
        if (m < M) {
            float4 o = make_float4(acc[i][0], acc[i][1], acc[i][2], acc[i][3]);
            *(float4*)&C[(size_t)m * DDIM + n0 + tx * 4] = o;
        }
    }
}

// ---------------------------------------------------------------------------
// Kernel 3: SpMM hop.  y[n,:] = sum_{e in [rp[n],rp[n+1])} w[e] * x[src[e],:]
// One block (128 threads) per destination node; thread t owns float4 #t of
// the 512-wide row (perfectly coalesced 2 KB row reads). Edge idx/weight
// loads are wave-uniform (L1 broadcast). 2-deep unroll, dual accumulators.
// ---------------------------------------------------------------------------
__global__ __launch_bounds__(128) void spmm_kernel(const float* __restrict__ x,
                                                   const int* __restrict__ esrc,
                                                   const float* __restrict__ ew,
                                                   const int* __restrict__ rp,
                                                   float* __restrict__ y) {
    const int n = blockIdx.x;
    const int t = threadIdx.x;  // 0..127
    const int s = rp[n];
    const int e = rp[n + 1];

    const float4* __restrict__ xv = (const float4*)x;
    float4 acc0 = make_float4(0.f, 0.f, 0.f, 0.f);
    float4 acc1 = make_float4(0.f, 0.f, 0.f, 0.f);

    int i = s;
    for (; i + 1 < e; i += 2) {
        const int s0 = esrc[i];
        const int s1 = esrc[i + 1];
        const float w0 = ew[i];
        const float w1 = ew[i + 1];
        float4 v0 = xv[(size_t)s0 * (DDIM / 4) + t];
        float4 v1 = xv[(size_t)s1 * (DDIM / 4) + t];
        acc0.x = fmaf(w0, v0.x, acc0.x);
        acc0.y = fmaf(w0, v0.y, acc0.y);
        acc0.z = fmaf(w0, v0.z, acc0.z);
        acc0.w = fmaf(w0, v0.w, acc0.w);
        acc1.x = fmaf(w1, v1.x, acc1.x);
        acc1.y = fmaf(w1, v1.y, acc1.y);
        acc1.z = fmaf(w1, v1.z, acc1.z);
        acc1.w = fmaf(w1, v1.w, acc1.w);
    }
    if (i < e) {
        const int s0 = esrc[i];
        const float w0 = ew[i];
        float4 v0 = xv[(size_t)s0 * (DDIM / 4) + t];
        acc0.x = fmaf(w0, v0.x, acc0.x);
        acc0.y = fmaf(w0, v0.y, acc0.y);
        acc0.z = fmaf(w0, v0.z, acc0.z);
        acc0.w = fmaf(w0, v0.w, acc0.w);
    }
    acc0.x += acc1.x; acc0.y += acc1.y; acc0.z += acc1.z; acc0.w += acc1.w;

    ((float4*)y)[(size_t)n * (DDIM / 4) + t] = acc0;
}

// ---------------------------------------------------------------------------
// Launch: rowptr -> gemm (X@W -> S in ws) -> spmm S->out -> out->S -> S->out
// ws layout: [rp: 100001 ints][pad to 512B][S: 100000*512 floats ~205 MB]
// ---------------------------------------------------------------------------
extern "C" void kernel_launch(void* const* d_in, const int* in_sizes, int n_in,
                              void* d_out, int out_size, void* d_ws, size_t ws_size,
                              hipStream_t stream) {
    const float* features = (const float*)d_in[0];
    const float* weight   = (const float*)d_in[1];
    const int*   esrc     = (const int*)d_in[2];
    const int*   edst     = (const int*)d_in[3];
    const float* ew       = (const float*)d_in[4];
    // d_in[5] = times (always 3 in this problem) -> 3 spmm hops total

    float* out = (float*)d_out;
    char*  ws  = (char*)d_ws;

    int* rp = (int*)ws;
    size_t rp_bytes = ((size_t)(N_NODES_C + 1) * sizeof(int) + 511) & ~(size_t)511;
    float* S = (float*)(ws + rp_bytes);

    build_rowptr<<<(N_NODES_C + 256) / 256, 256, 0, stream>>>(edst, rp);

    dim3 ggrid((N_NODES_C + BM - 1) / BM, DDIM / BN);
    gemm_f32<<<ggrid, 256, 0, stream>>>(features, weight, S, N_NODES_C);

    spmm_kernel<<<N_NODES_C, 128, 0, stream>>>(S,   esrc, ew, rp, out);
    spmm_kernel<<<N_NODES_C, 128, 0, stream>>>(out, esrc, ew, rp, S);
    spmm_kernel<<<N_NODES_C, 128, 0, stream>>>(S,   esrc, ew, rp, out);
}